// Round 7
// baseline (325.415 us; speedup 1.0000x reference)
//
#include <hip/hip_runtime.h>
#include <math.h>

namespace {

typedef unsigned short u16;
typedef unsigned int u32;
typedef __attribute__((ext_vector_type(8))) short bf16x8;
typedef __attribute__((ext_vector_type(4))) float f32x4;
typedef __attribute__((ext_vector_type(2))) float f32x2;
typedef __attribute__((ext_vector_type(2))) unsigned int u32x2;

constexpr int HDIM = 64;
constexpr int WDIM = 64;
constexpr int HW = HDIM * WDIM;   // 4096
constexpr int C = 512;
constexpr int G = 4;
constexpr int CG = 128;
constexpr int K = 9;
constexpr int NH = 8;
constexpr float SCALE = 0.125f;   // DH^-0.5

__device__ __forceinline__ u16 f2b(float f) {
  union { float f; u32 u; } v; v.f = f;
  u32 u = v.u;
  return (u16)((u + 0x7FFFu + ((u >> 16) & 1u)) >> 16);
}
__device__ __forceinline__ float b2f(u16 b) {
  union { u32 u; float f; } v; v.u = ((u32)b) << 16;
  return v.f;
}

// ---------- merged one-time prep: wq/wv/wo->bf16, wkT, x transpose ----------
// blocks [0,1024): convert3; [1024,1280): wkT; [1280,3328): transpose
__global__ void __launch_bounds__(256)
k_prep(const float* __restrict__ wq, const float* __restrict__ wv,
       const float* __restrict__ wo, const float* __restrict__ wk,
       const float* __restrict__ x,
       u16* __restrict__ wqb, u16* __restrict__ wvb, u16* __restrict__ wob,
       u16* __restrict__ wkT, u16* __restrict__ xtb) {
  int b = blockIdx.x;
  int t = threadIdx.x;
  if (b < 1024) {
    int j = b * 256 + t;
    wqb[j] = f2b(wq[j]);
    wvb[j] = f2b(wv[j]);
    wob[j] = f2b(wo[j]);
    return;
  }
  __shared__ float tile[32][33];
  int tx = t & 31, ty = t >> 5;
  if (b < 1280) {
    int bb = b - 1024;                       // grid was (16,16)
    int r0 = (bb & 15) * 32, c0 = (bb >> 4) * 32;
    for (int r = ty; r < 32; r += 8) tile[r][tx] = wk[(r0 + r) * C + c0 + tx];
    __syncthreads();
    for (int r = ty; r < 32; r += 8) wkT[(c0 + r) * C + r0 + tx] = f2b(tile[tx][r]);
  } else {
    int bb = b - 1280;                       // grid was (128,16)
    int p0 = (bb & 127) * 32, c0 = (bb >> 7) * 32;
    for (int r = ty; r < 32; r += 8) tile[r][tx] = x[(c0 + r) * HW + p0 + tx];
    __syncthreads();
    for (int r = ty; r < 32; r += 8) xtb[(p0 + r) * C + c0 + tx] = f2b(tile[tx][r]);
  }
}

// ---------- small-tile bf16 MFMA GEMM: 32x32 block (4 waves, 1 tile each) ----------
// D[m][n] = sum_k A[m][k] * BT[n][k] (+bias[n]); 4x the block count of the 64-tile
// version -> 4-8 waves/SIMD for latency hiding (GEMM3/4 were at 1 wave/SIMD).
template <bool OUT_BF16>
__global__ void __launch_bounds__(256)
k_gemm_s(const u16* __restrict__ A, int lda, int aOffZ,
         const u16* __restrict__ BT, int ldb, int bOffZ,
         const float* __restrict__ bias, int biasOffZ,
         void* __restrict__ Dp, int ldd, int dOffZ, int Kd,
         const int* __restrict__ labels, float* __restrict__ sigp) {
  int z = blockIdx.z;
  const u16* Ab = A + (size_t)z * aOffZ;
  const u16* Bb = BT + (size_t)z * bOffZ;
  int t = threadIdx.x;
  int wave = t >> 6, lane = t & 63;
  int bm = blockIdx.x * 32 + (wave >> 1) * 16;
  int bn = blockIdx.y * 32 + (wave & 1) * 16;
  int row = lane & 15, quad = lane >> 4;
  const u16* ap = &Ab[(size_t)(bm + row) * lda + quad * 8];
  const u16* bp = &Bb[(size_t)(bn + row) * ldb + quad * 8];
  f32x4 acc = {};
#pragma unroll 4
  for (int k0 = 0; k0 < Kd; k0 += 32) {
    bf16x8 a = *(const bf16x8*)(ap + k0);
    bf16x8 b = *(const bf16x8*)(bp + k0);
    acc = __builtin_amdgcn_mfma_f32_16x16x32_bf16(a, b, acc, 0, 0, 0);
  }
  int cc = bn + row;
  float bb = bias ? bias[(size_t)z * biasOffZ + cc] : 0.0f;
#pragma unroll
  for (int r = 0; r < 4; ++r) {
    int rr = bm + quad * 4 + r;
    float v = acc[r] + bb;
    if (OUT_BF16) {
      ((u16*)Dp)[(size_t)z * dOffZ + (size_t)rr * ldd + cc] = f2b(v);
    } else {
      ((float*)Dp)[(size_t)z * dOffZ + (size_t)rr * ldd + cc] = v;
      if (labels && labels[rr] == cc) sigp[rr] = 1.0f / (1.0f + expf(-v));
    }
  }
}

// ---------- merged: dwconv+LN+GELU full map (blocks [0,HW)) || GEMM2 (blocks [HW,HW+2048)) ----------
// the two halves are data-independent (both read q_tb) and fill the machine concurrently.
__global__ void __launch_bounds__(256)
k_mix(const u16* __restrict__ q_tb, const float* __restrict__ w9,
      const float* __restrict__ wb, const float* __restrict__ lng,
      const float* __restrict__ lnb, u16* __restrict__ t1b,
      const u16* __restrict__ wkT, const int* __restrict__ idx,
      u16* __restrict__ qk2b) {
  int b = blockIdx.x;
  int t = threadIdx.x;
  if (b < HW) {
    // ---- dwln2 path: one spatial position, 2 channels/thread, wave == LN group ----
    int p = b;
    int h = p >> 6, w = p & 63;
    int c0 = t * 2;
    int cg0 = c0 & 127, cg1 = cg0 + 1;
    float a0 = wb[cg0], a1 = wb[cg1];
#pragma unroll
    for (int dy = 0; dy < 3; ++dy) {
      int hh = h + dy - 1;
      if (hh < 0 || hh >= HDIM) continue;
#pragma unroll
      for (int dx = 0; dx < 3; ++dx) {
        int ww = w + dx - 1;
        if (ww < 0 || ww >= WDIM) continue;
        u32 pr2 = *(const u32*)&q_tb[(hh * WDIM + ww) * C + c0];
        float wt0 = w9[cg0 * 9 + dy * 3 + dx];
        float wt1 = w9[cg1 * 9 + dy * 3 + dx];
        a0 += wt0 * b2f((u16)pr2);
        a1 += wt1 * b2f((u16)(pr2 >> 16));
      }
    }
    float s = a0 + a1, s2 = a0 * a0 + a1 * a1;
#pragma unroll
    for (int o = 32; o > 0; o >>= 1) {
      s += __shfl_xor(s, o, 64);
      s2 += __shfl_xor(s2, o, 64);
    }
    float mean = s * (1.0f / 128.0f);
    float var = s2 * (1.0f / 128.0f) - mean * mean;
    float rstd = rsqrtf(var + 1e-5f);
    float xn0 = (a0 - mean) * rstd * lng[cg0] + lnb[cg0];
    float xn1 = (a1 - mean) * rstd * lng[cg1] + lnb[cg1];
    u16 o0 = f2b(0.5f * xn0 * (1.0f + erff(xn0 * 0.70710678f)));
    u16 o1 = f2b(0.5f * xn1 * (1.0f + erff(xn1 * 0.70710678f)));
    *(u32*)&t1b[(size_t)p * C + c0] = ((u32)o1 << 16) | o0;
  } else {
    // ---- GEMM2 path: qk2b[i][z*512+c'] = sum_d q_tb[p_i][z*64+d] * wkT[c'][z*64+d] ----
    int bb = b - HW;                  // 0..2047
    int m = bb & 31, nn = (bb >> 5) & 7, z = bb >> 8;
    const u16* Ab = q_tb + z * 64;
    const u16* Bb = wkT + z * 64;
    int wave = t >> 6, lane = t & 63;
    int wm = (wave >> 1) * 32, wn = (wave & 1) * 32;
    int bm = m * 64 + wm;
    int bn = nn * 64 + wn;
    int row = lane & 15, quad = lane >> 4;
    size_t ar[2];
#pragma unroll
    for (int mt = 0; mt < 2; ++mt) {
      int r = bm + mt * 16 + row;
      ar[mt] = (size_t)(idx[2 * r] * WDIM + idx[2 * r + 1]);
    }
    f32x4 acc[2][2] = {};
#pragma unroll
    for (int k0 = 0; k0 < 64; k0 += 32) {
      bf16x8 a[2], bfr[2];
#pragma unroll
      for (int mt = 0; mt < 2; ++mt)
        a[mt] = *(const bf16x8*)&Ab[ar[mt] * C + k0 + quad * 8];
#pragma unroll
      for (int nt = 0; nt < 2; ++nt)
        bfr[nt] = *(const bf16x8*)&Bb[(size_t)(bn + nt * 16 + row) * C + k0 + quad * 8];
#pragma unroll
      for (int mt = 0; mt < 2; ++mt)
#pragma unroll
        for (int nt = 0; nt < 2; ++nt)
          acc[mt][nt] = __builtin_amdgcn_mfma_f32_16x16x32_bf16(a[mt], bfr[nt], acc[mt][nt], 0, 0, 0);
    }
#pragma unroll
    for (int nt = 0; nt < 2; ++nt) {
      int cc = bn + nt * 16 + row;
#pragma unroll
      for (int mt = 0; mt < 2; ++mt)
#pragma unroll
        for (int r = 0; r < 4; ++r) {
          int rr = bm + mt * 16 + quad * 4 + r;
          qk2b[(size_t)rr * (NH * C) + z * C + cc] = f2b(acc[mt][nt][r]);
        }
    }
  }
}

// ---------- fused pass-2 at selected points only: dwconv+LN+GELU + offset matvec + tanh + pos ----------
// block = one point; wave = one group; zero LDS, zero __syncthreads.
__global__ void __launch_bounds__(256)
k_dwoff(const u16* __restrict__ t1, const float* __restrict__ w9,
        const float* __restrict__ wb, const float* __restrict__ lng,
        const float* __restrict__ lnb, const float* __restrict__ ow3,
        const int* __restrict__ idx, float* __restrict__ pos) {
  int i = blockIdx.x;
  int t = threadIdx.x;
  int iy = idx[2 * i], ix = idx[2 * i + 1];
  int c0 = t * 2;
  int cg0 = c0 & 127, cg1 = cg0 + 1;
  int g = t >> 6;        // wave == group
  int lane = t & 63;
  // depthwise 3x3 at the point (SAME zero-pad)
  float a0 = wb[cg0], a1 = wb[cg1];
#pragma unroll
  for (int dy = 0; dy < 3; ++dy) {
    int hh = iy + dy - 1;
    if (hh < 0 || hh >= HDIM) continue;
#pragma unroll
    for (int dx = 0; dx < 3; ++dx) {
      int ww = ix + dx - 1;
      if (ww < 0 || ww >= WDIM) continue;
      u32 pr2 = *(const u32*)&t1[(hh * WDIM + ww) * C + c0];
      float wt0 = w9[cg0 * 9 + dy * 3 + dx];
      float wt1 = w9[cg1 * 9 + dy * 3 + dx];
      a0 += wt0 * b2f((u16)pr2);
      a1 += wt1 * b2f((u16)(pr2 >> 16));
    }
  }
  // LN over the 128-ch group (wave-local shuffle reduce)
  float s = a0 + a1, s2 = a0 * a0 + a1 * a1;
#pragma unroll
  for (int o = 32; o > 0; o >>= 1) {
    s += __shfl_xor(s, o, 64);
    s2 += __shfl_xor(s2, o, 64);
  }
  float mean = s * (1.0f / 128.0f);
  float var = s2 * (1.0f / 128.0f) - mean * mean;
  float rstd = rsqrtf(var + 1e-5f);
  float xn0 = (a0 - mean) * rstd * lng[cg0] + lnb[cg0];
  float xn1 = (a1 - mean) * rstd * lng[cg1] + lnb[cg1];
  float x0 = 0.5f * xn0 * (1.0f + erff(xn0 * 0.70710678f));
  float x1 = 0.5f * xn1 * (1.0f + erff(xn1 * 0.70710678f));
  // offset matvec: ov[l] = sum_c ow3[l][c] * t2[g][c], 18 wave-reductions
  float ovreg = 0.0f;
#pragma unroll
  for (int l = 0; l < 18; ++l) {
    float a = ow3[l * CG + cg0] * x0 + ow3[l * CG + cg1] * x1;
#pragma unroll
    for (int o = 32; o > 0; o >>= 1) a += __shfl_xor(a, o, 64);
    if (lane == l) ovreg = a;
  }
  // lanes 0..8 -> tanh + reference grid -> pos
  int ls = (lane < 9) ? lane : 0;
  float vy = __shfl(ovreg, 2 * ls, 64);
  float vx = __shfl(ovreg, 2 * ls + 1, 64);
  if (lane < 9) {
    int dy = lane / 3, dx = lane % 3;
    int ryi = min(max(iy + dy - 1, 0), HDIM - 1);
    int rxi = min(max(ix + dx - 1, 0), WDIM - 1);
    float ry = (ryi + 0.5f) * (2.0f / HDIM) - 1.0f;
    float rx = (rxi + 0.5f) * (2.0f / WDIM) - 1.0f;
    f32x2 pv;
    pv.x = tanhf(vy) * (2.0f / HDIM) + ry;
    pv.y = tanhf(vx) * (2.0f / WDIM) + rx;
    *(f32x2*)&pos[((i * G + g) * K + lane) * 2] = pv;
  }
}

// ---------- fused: full-C bilinear sample (-> xr) + attention ----------
// 4 phases / 3 barriers: softmax folded into z-phase (redundant per-wave recompute),
// z-phase reads xsl at consecutive 16B/lane (full bank coverage) + coalesced 1KB row stores.
__global__ void __launch_bounds__(256)
k_attn5(const u16* __restrict__ qk2b, const u16* __restrict__ xtb,
        const float* __restrict__ pos, float* __restrict__ attn_out,
        u16* __restrict__ z2b, float* __restrict__ xr, int n) {
  constexpr int LD = 520;  // row stride (u16) -> 1040 B
  int i = blockIdx.x;
  int t = threadIdx.x;
  __shared__ alignas(16) u16 qkl[8 * LD];
  __shared__ alignas(16) u16 xsl[16 * LD];
  __shared__ int ro[36][4];
  __shared__ float wbl[36][4];
  __shared__ float lg[NH][K];
  // vectorized staging of the 8 KB qk row: 2 x dwordx4 per thread
  {
    const bf16x8* qs = (const bf16x8*)(qk2b + (size_t)i * (NH * C));
#pragma unroll
    for (int cix = t; cix < 512; cix += 256) {
      bf16x8 val = qs[cix];
      int r = cix >> 6;
      int co = (cix & 63) * 8;
      *(bf16x8*)&qkl[r * LD + co] = val;
    }
  }
  // 36 threads precompute bilinear taps once per block
  if (t < 36) {
    float py = pos[(size_t)i * 72 + 2 * t];
    float px = pos[(size_t)i * 72 + 2 * t + 1];
    float gx = (px + 1.0f) * 0.5f * (WDIM - 1);
    float gy = (py + 1.0f) * 0.5f * (HDIM - 1);
    float x0f = floorf(gx), y0f = floorf(gy);
    float wx1 = gx - x0f, wx0 = 1.0f - wx1;
    float wy1 = gy - y0f, wy0 = 1.0f - wy1;
    int x0 = (int)x0f, y0 = (int)y0f;
    int x1 = x0 + 1, y1 = y0 + 1;
    bool vx0 = (x0 >= 0) && (x0 < WDIM);
    bool vx1 = (x1 >= 0) && (x1 < WDIM);
    bool vy0 = (y0 >= 0) && (y0 < HDIM);
    bool vy1 = (y1 >= 0) && (y1 < HDIM);
    wbl[t][0] = (vy0 && vx0) ? wy0 * wx0 : 0.0f;
    wbl[t][1] = (vy0 && vx1) ? wy0 * wx1 : 0.0f;
    wbl[t][2] = (vy1 && vx0) ? wy1 * wx0 : 0.0f;
    wbl[t][3] = (vy1 && vx1) ? wy1 * wx1 : 0.0f;
    int x0c = min(max(x0, 0), WDIM - 1), x1c = min(max(x1, 0), WDIM - 1);
    int y0c = min(max(y0, 0), HDIM - 1), y1c = min(max(y1, 0), HDIM - 1);
    ro[t][0] = (y0c * WDIM + x0c) * C;
    ro[t][1] = (y0c * WDIM + x1c) * C;
    ro[t][2] = (y1c * WDIM + x0c) * C;
    ro[t][3] = (y1c * WDIM + x1c) * C;
  }
  __syncthreads();
  int wave = t >> 6;
  float* xrb = xr + (size_t)i * (G * K) * C;
  // full-C gather: 4 channels/thread, 2 positions in parallel.
  {
    int half = t >> 7;       // 0/1: which position of the pair
    int th = t & 127;
    int c4 = th * 4;         // 4 channels
#pragma unroll 3
    for (int j = 0; j < 18; ++j) {
      int it = 2 * j + half;
      float w00 = wbl[it][0], w01 = wbl[it][1], w10 = wbl[it][2], w11 = wbl[it][3];
      u32x2 q00 = *(const u32x2*)&xtb[ro[it][0] + c4];
      u32x2 q01 = *(const u32x2*)&xtb[ro[it][1] + c4];
      u32x2 q10 = *(const u32x2*)&xtb[ro[it][2] + c4];
      u32x2 q11 = *(const u32x2*)&xtb[ro[it][3] + c4];
      float v0 = w00 * b2f((u16)q00.x) + w01 * b2f((u16)q01.x) +
                 w10 * b2f((u16)q10.x) + w11 * b2f((u16)q11.x);
      float v1 = w00 * b2f((u16)(q00.x >> 16)) + w01 * b2f((u16)(q01.x >> 16)) +
                 w10 * b2f((u16)(q10.x >> 16)) + w11 * b2f((u16)(q11.x >> 16));
      float v2 = w00 * b2f((u16)q00.y) + w01 * b2f((u16)q01.y) +
                 w10 * b2f((u16)q10.y) + w11 * b2f((u16)q11.y);
      float v3 = w00 * b2f((u16)(q00.y >> 16)) + w01 * b2f((u16)(q01.y >> 16)) +
                 w10 * b2f((u16)(q10.y >> 16)) + w11 * b2f((u16)(q11.y >> 16));
      f32x4 ov = {v0, v1, v2, v3};
      __builtin_nontemporal_store(ov, (f32x4*)&xrb[(size_t)it * C + c4]);
      int gi = (it * 57) >> 9;       // it / 9
      if ((th >> 5) == gi) {         // this thread's channels are in group gi's slice
        int kk = it - gi * 9;
        u32x2 pk;
        pk.x = ((u32)f2b(v1) << 16) | f2b(v0);
        pk.y = ((u32)f2b(v3) << 16) | f2b(v2);
        *(u32x2*)&xsl[kk * LD + c4] = pk;
      }
    }
  }
  __syncthreads();
  // logits: one wave, one 16x16 MFMA tile over K=512; A rows 8-15 duplicate rows 0-7 (discarded)
  if (wave == 0) {
    int lane = t & 63;
    int row = lane & 15, quad = lane >> 4;
    f32x4 acc = {};
    __builtin_amdgcn_s_setprio(1);
#pragma unroll 4
    for (int k0 = 0; k0 < C; k0 += 32) {
      bf16x8 a = *(const bf16x8*)&qkl[(row & 7) * LD + k0 + quad * 8];
      bf16x8 b = *(const bf16x8*)&xsl[row * LD + k0 + quad * 8];
      acc = __builtin_amdgcn_mfma_f32_16x16x32_bf16(a, b, acc, 0, 0, 0);
    }
    __builtin_amdgcn_s_setprio(0);
    if (row < K && quad < 2) {
#pragma unroll
      for (int r = 0; r < 4; ++r) lg[quad * 4 + r][row] = acc[r] * SCALE;
    }
  }
  __syncthreads();
  // z-phase + inline softmax: wave w owns heads {2w, 2w+1}; lane l covers chunk l (8 ch).
  {
    int lane = t & 63;
    u16* zrow = z2b + (size_t)i * (NH * C);
#pragma unroll
    for (int hh = 0; hh < 2; ++hh) {
      int h = wave * 2 + hh;
      float mx = -1e30f;
#pragma unroll
      for (int kk = 0; kk < K; ++kk) mx = fmaxf(mx, lg[h][kk]);
      float e[K];
      float sm = 0.0f;
#pragma unroll
      for (int kk = 0; kk < K; ++kk) { e[kk] = expf(lg[h][kk] - mx); sm += e[kk]; }
      float inv = 1.0f / sm;
      if (lane < K) attn_out[((size_t)h * n + i) * K + lane] = e[lane] * inv;
      float accz[8] = {};
#pragma unroll
      for (int kk = 0; kk < K; ++kk) {
        bf16x8 v = *(const bf16x8*)&xsl[kk * LD + lane * 8];
        float p = e[kk] * inv;
#pragma unroll
        for (int el = 0; el < 8; ++el) accz[el] += p * b2f((u16)v[el]);
      }
      u16 ob[8];
#pragma unroll
      for (int el = 0; el < 8; ++el) ob[el] = f2b(accz[el]);
      *(bf16x8*)&zrow[h * C + lane * 8] = *(const bf16x8*)ob;
    }
  }
}

}  // namespace

extern "C" void kernel_launch(void* const* d_in, const int* in_sizes, int n_in,
                              void* d_out, int out_size, void* d_ws, size_t ws_size,
                              hipStream_t stream) {
  (void)n_in; (void)out_size; (void)ws_size;
  const float* x = (const float*)d_in[0];
  const int* idx = (const int*)d_in[1];
  const int* labels = (const int*)d_in[2];
  const float* wq = (const float*)d_in[3];
  const float* bq = (const float*)d_in[4];
  const float* wk = (const float*)d_in[5];
  // bk (d_in[6]) cancels exactly in softmax — unused.
  const float* wv = (const float*)d_in[7];
  const float* bv = (const float*)d_in[8];
  const float* wo = (const float*)d_in[9];
  const float* bo = (const float*)d_in[10];
  const float* ow1 = (const float*)d_in[11];
  const float* ob1 = (const float*)d_in[12];
  const float* g1 = (const float*)d_in[13];
  const float* b1 = (const float*)d_in[14];
  const float* ow2 = (const float*)d_in[15];
  const float* ob2 = (const float*)d_in[16];
  const float* g2 = (const float*)d_in[17];
  const float* b2 = (const float*)d_in[18];
  const float* ow3 = (const float*)d_in[19];
  int n = in_sizes[1] / 2;  // 2048

  unsigned char* wp = (unsigned char*)d_ws;
  auto alloc = [&](size_t bytes) {
    unsigned char* p = wp;
    wp += (bytes + 255) & ~(size_t)255;
    return p;
  };
  u16* xtb = (u16*)alloc((size_t)HW * C * 2);
  u16* wqb = (u16*)alloc((size_t)C * C * 2);
  u16* wvb = (u16*)alloc((size_t)C * C * 2);
  u16* wob = (u16*)alloc((size_t)C * C * 2);
  u16* wkT = (u16*)alloc((size_t)C * C * 2);
  u16* q_tb = (u16*)alloc((size_t)HW * C * 2);
  u16* t1b = (u16*)alloc((size_t)HW * C * 2);
  u16* qk2b = (u16*)alloc((size_t)n * NH * C * 2);
  float* pos = (float*)alloc((size_t)n * G * K * 2 * 4);
  u16* z2b = (u16*)alloc((size_t)n * NH * C * 2);
  u16* outb = (u16*)alloc((size_t)n * C * 2);

  // output layout: y (n,C) | attn (NH,n,K) | xr_sel (n,G*K,C) | sig (n)
  float* out_f = (float*)d_out;
  float* y_out = out_f;
  float* attn_out = y_out + (size_t)n * C;
  float* xr_out = attn_out + (size_t)NH * n * K;
  float* sig_out = xr_out + (size_t)n * G * K * C;

  // prep: weight converts + wkT + x transpose (merged)
  k_prep<<<dim3(3328), 256, 0, stream>>>(wq, wv, wo, wk, x, wqb, wvb, wob, wkT, xtb);

  // GEMM1: q_tb[p][c] = sum_k xtb[p][k] * wqb[c][k] + bq[c]  (bf16 out)
  // 32x32 tiles: 128x16 = 2048 blocks (8/CU)
  k_gemm_s<true><<<dim3(HW / 32, C / 32, 1), 256, 0, stream>>>(
      xtb, C, 0, wqb, C, 0, bq, 0, q_tb, C, 0, C, nullptr, nullptr);

  // dwln pass-1 (full map)  ||  GEMM2 (per-head q.K projection) — one launch
  k_mix<<<dim3(HW + 2048), 256, 0, stream>>>(q_tb, ow1, ob1, g1, b1, t1b, wkT, idx, qk2b);

  // fused pass-2 + offsets at selected points only
  k_dwoff<<<dim3(n), 256, 0, stream>>>(t1b, ow2, ob2, g2, b2, ow3, idx, pos);

  // fused sample + attention
  k_attn5<<<dim3(n), 256, 0, stream>>>(qk2b, xtb, pos, attn_out, z2b, xr_out, n);

  // GEMM3 (per head): outb[i][h*64+d] = sum_c' z2b[i][h*512+c'] * wvb[h*64+d][c'] + bv
  // 32x32 tiles: 64x2x8 = 1024 blocks (4/CU)
  k_gemm_s<true><<<dim3(n / 32, 2, NH), 256, 0, stream>>>(
      z2b, NH * C, C, wvb, C, 64 * C, bv, 64, outb, C, 64, C, nullptr, nullptr);

  // GEMM4: y[i][co] = sum_c outb[i][c] * wob[co][c] + bo[co]  (fp32 out) + fused sigmoid
  // 32x32 tiles: 64x16 = 1024 blocks (4/CU)
  k_gemm_s<false><<<dim3(n / 32, C / 32, 1), 256, 0, stream>>>(
      outb, C, 0, wob, C, 0, bo, 0, y_out, C, 0, C, labels, sig_out);
}

// Round 8
// 305.555 us; speedup vs baseline: 1.0650x; 1.0650x over previous
//
#include <hip/hip_runtime.h>
#include <math.h>

namespace {

typedef unsigned short u16;
typedef unsigned int u32;
typedef __attribute__((ext_vector_type(8))) short bf16x8;
typedef __attribute__((ext_vector_type(4))) float f32x4;
typedef __attribute__((ext_vector_type(2))) float f32x2;
typedef __attribute__((ext_vector_type(2))) unsigned int u32x2;

constexpr int HDIM = 64;
constexpr int WDIM = 64;
constexpr int HW = HDIM * WDIM;   // 4096
constexpr int C = 512;
constexpr int G = 4;
constexpr int CG = 128;
constexpr int K = 9;
constexpr int NH = 8;
constexpr float SCALE = 0.125f;   // DH^-0.5

__device__ __forceinline__ u16 f2b(float f) {
  union { float f; u32 u; } v; v.f = f;
  u32 u = v.u;
  return (u16)((u + 0x7FFFu + ((u >> 16) & 1u)) >> 16);
}
__device__ __forceinline__ float b2f(u16 b) {
  union { u32 u; float f; } v; v.u = ((u32)b) << 16;
  return v.f;
}

// ---------- merged one-time prep: wq/wv/wo->bf16, wkT, x transpose ----------
// blocks [0,1024): convert3; [1024,1280): wkT; [1280,3328): transpose
__global__ void __launch_bounds__(256)
k_prep(const float* __restrict__ wq, const float* __restrict__ wv,
       const float* __restrict__ wo, const float* __restrict__ wk,
       const float* __restrict__ x,
       u16* __restrict__ wqb, u16* __restrict__ wvb, u16* __restrict__ wob,
       u16* __restrict__ wkT, u16* __restrict__ xtb) {
  int b = blockIdx.x;
  int t = threadIdx.x;
  if (b < 1024) {
    int j = b * 256 + t;
    wqb[j] = f2b(wq[j]);
    wvb[j] = f2b(wv[j]);
    wob[j] = f2b(wo[j]);
    return;
  }
  __shared__ float tile[32][33];
  int tx = t & 31, ty = t >> 5;
  if (b < 1280) {
    int bb = b - 1024;                       // grid was (16,16)
    int r0 = (bb & 15) * 32, c0 = (bb >> 4) * 32;
    for (int r = ty; r < 32; r += 8) tile[r][tx] = wk[(r0 + r) * C + c0 + tx];
    __syncthreads();
    for (int r = ty; r < 32; r += 8) wkT[(c0 + r) * C + r0 + tx] = f2b(tile[tx][r]);
  } else {
    int bb = b - 1280;                       // grid was (128,16)
    int p0 = (bb & 127) * 32, c0 = (bb >> 7) * 32;
    for (int r = ty; r < 32; r += 8) tile[r][tx] = x[(c0 + r) * HW + p0 + tx];
    __syncthreads();
    for (int r = ty; r < 32; r += 8) xtb[(p0 + r) * C + c0 + tx] = f2b(tile[tx][r]);
  }
}

// ---------- unified bf16 MFMA GEMM: D[m][n] = sum_k A[m][k] * BT[n][k] (+bias[n]) ----------
// KD compile-time -> K-loop unrollable -> loads for 4 K-steps issued ahead (ILP latency hiding;
// these kernels run at 1-2 waves/SIMD so TLP alone cannot hide L2 latency).
template <bool OUT_BF16, int KD>
__global__ void __launch_bounds__(256)
k_gemm_mfma(const u16* __restrict__ A, int lda, int aOffZ,
            const int* __restrict__ aIdx,
            const u16* __restrict__ BT, int ldb, int bOffZ,
            const float* __restrict__ bias, int biasOffZ,
            void* __restrict__ Dp, int ldd, int dOffZ,
            const int* __restrict__ labels, float* __restrict__ sigp) {
  int z = blockIdx.z;
  const u16* Ab = A + (size_t)z * aOffZ;
  const u16* Bb = BT + (size_t)z * bOffZ;
  int t = threadIdx.x;
  int wave = t >> 6, lane = t & 63;
  int wm = (wave >> 1) * 32, wn = (wave & 1) * 32;
  int bm = blockIdx.x * 64 + wm;
  int bn = blockIdx.y * 64 + wn;
  int row = lane & 15, quad = lane >> 4;
  size_t ar[2];
#pragma unroll
  for (int mt = 0; mt < 2; ++mt) {
    int r = bm + mt * 16 + row;
    ar[mt] = aIdx ? (size_t)(aIdx[2 * r] * WDIM + aIdx[2 * r + 1]) : (size_t)r;
  }
  f32x4 acc[2][2] = {};
#pragma unroll 4
  for (int k0 = 0; k0 < KD; k0 += 32) {
    bf16x8 a[2], b[2];
#pragma unroll
    for (int mt = 0; mt < 2; ++mt)
      a[mt] = *(const bf16x8*)&Ab[ar[mt] * lda + k0 + quad * 8];
#pragma unroll
    for (int nt = 0; nt < 2; ++nt)
      b[nt] = *(const bf16x8*)&Bb[(size_t)(bn + nt * 16 + row) * ldb + k0 + quad * 8];
#pragma unroll
    for (int mt = 0; mt < 2; ++mt)
#pragma unroll
      for (int nt = 0; nt < 2; ++nt)
        acc[mt][nt] = __builtin_amdgcn_mfma_f32_16x16x32_bf16(a[mt], b[nt], acc[mt][nt], 0, 0, 0);
  }
#pragma unroll
  for (int nt = 0; nt < 2; ++nt) {
    int cc = bn + nt * 16 + row;
    float bb = bias ? bias[(size_t)z * biasOffZ + cc] : 0.0f;
#pragma unroll
    for (int mt = 0; mt < 2; ++mt)
#pragma unroll
      for (int r = 0; r < 4; ++r) {
        int rr = bm + mt * 16 + quad * 4 + r;
        float v = acc[mt][nt][r] + bb;
        if (OUT_BF16) {
          ((u16*)Dp)[(size_t)z * dOffZ + (size_t)rr * ldd + cc] = f2b(v);
        } else {
          ((float*)Dp)[(size_t)z * dOffZ + (size_t)rr * ldd + cc] = v;
          if (labels && labels[rr] == cc) sigp[rr] = 1.0f / (1.0f + expf(-v));
        }
      }
  }
}

// ---------- merged: dwconv+LN+GELU full map (blocks [0,HW)) || GEMM2 (blocks [HW,HW+2048)) ----------
// the two halves are data-independent (both read q_tb) and fill the machine concurrently.
__global__ void __launch_bounds__(256)
k_mix(const u16* __restrict__ q_tb, const float* __restrict__ w9,
      const float* __restrict__ wb, const float* __restrict__ lng,
      const float* __restrict__ lnb, u16* __restrict__ t1b,
      const u16* __restrict__ wkT, const int* __restrict__ idx,
      u16* __restrict__ qk2b) {
  int b = blockIdx.x;
  int t = threadIdx.x;
  if (b < HW) {
    // ---- dwln2 path: one spatial position, 2 channels/thread, wave == LN group ----
    int p = b;
    int h = p >> 6, w = p & 63;
    int c0 = t * 2;
    int cg0 = c0 & 127, cg1 = cg0 + 1;
    float a0 = wb[cg0], a1 = wb[cg1];
#pragma unroll
    for (int dy = 0; dy < 3; ++dy) {
      int hh = h + dy - 1;
      if (hh < 0 || hh >= HDIM) continue;
#pragma unroll
      for (int dx = 0; dx < 3; ++dx) {
        int ww = w + dx - 1;
        if (ww < 0 || ww >= WDIM) continue;
        u32 pr2 = *(const u32*)&q_tb[(hh * WDIM + ww) * C + c0];
        float wt0 = w9[cg0 * 9 + dy * 3 + dx];
        float wt1 = w9[cg1 * 9 + dy * 3 + dx];
        a0 += wt0 * b2f((u16)pr2);
        a1 += wt1 * b2f((u16)(pr2 >> 16));
      }
    }
    float s = a0 + a1, s2 = a0 * a0 + a1 * a1;
#pragma unroll
    for (int o = 32; o > 0; o >>= 1) {
      s += __shfl_xor(s, o, 64);
      s2 += __shfl_xor(s2, o, 64);
    }
    float mean = s * (1.0f / 128.0f);
    float var = s2 * (1.0f / 128.0f) - mean * mean;
    float rstd = rsqrtf(var + 1e-5f);
    float xn0 = (a0 - mean) * rstd * lng[cg0] + lnb[cg0];
    float xn1 = (a1 - mean) * rstd * lng[cg1] + lnb[cg1];
    u16 o0 = f2b(0.5f * xn0 * (1.0f + erff(xn0 * 0.70710678f)));
    u16 o1 = f2b(0.5f * xn1 * (1.0f + erff(xn1 * 0.70710678f)));
    *(u32*)&t1b[(size_t)p * C + c0] = ((u32)o1 << 16) | o0;
  } else {
    // ---- GEMM2 path: qk2b[i][z*512+c'] = sum_d q_tb[p_i][z*64+d] * wkT[c'][z*64+d] ----
    int bb = b - HW;                  // 0..2047
    int m = bb & 31, nn = (bb >> 5) & 7, z = bb >> 8;
    const u16* Ab = q_tb + z * 64;
    const u16* Bb = wkT + z * 64;
    int wave = t >> 6, lane = t & 63;
    int wm = (wave >> 1) * 32, wn = (wave & 1) * 32;
    int bm = m * 64 + wm;
    int bn = nn * 64 + wn;
    int row = lane & 15, quad = lane >> 4;
    size_t ar[2];
#pragma unroll
    for (int mt = 0; mt < 2; ++mt) {
      int r = bm + mt * 16 + row;
      ar[mt] = (size_t)(idx[2 * r] * WDIM + idx[2 * r + 1]);
    }
    f32x4 acc[2][2] = {};
#pragma unroll
    for (int k0 = 0; k0 < 64; k0 += 32) {
      bf16x8 a[2], bfr[2];
#pragma unroll
      for (int mt = 0; mt < 2; ++mt)
        a[mt] = *(const bf16x8*)&Ab[ar[mt] * C + k0 + quad * 8];
#pragma unroll
      for (int nt = 0; nt < 2; ++nt)
        bfr[nt] = *(const bf16x8*)&Bb[(size_t)(bn + nt * 16 + row) * C + k0 + quad * 8];
#pragma unroll
      for (int mt = 0; mt < 2; ++mt)
#pragma unroll
        for (int nt = 0; nt < 2; ++nt)
          acc[mt][nt] = __builtin_amdgcn_mfma_f32_16x16x32_bf16(a[mt], bfr[nt], acc[mt][nt], 0, 0, 0);
    }
#pragma unroll
    for (int nt = 0; nt < 2; ++nt) {
      int cc = bn + nt * 16 + row;
#pragma unroll
      for (int mt = 0; mt < 2; ++mt)
#pragma unroll
        for (int r = 0; r < 4; ++r) {
          int rr = bm + mt * 16 + quad * 4 + r;
          qk2b[(size_t)rr * (NH * C) + z * C + cc] = f2b(acc[mt][nt][r]);
        }
    }
  }
}

// ---------- fused pass-2 at selected points only: dwconv+LN+GELU + offset matvec + tanh + pos ----------
// block = one point; wave = one group; zero LDS, zero __syncthreads.
__global__ void __launch_bounds__(256)
k_dwoff(const u16* __restrict__ t1, const float* __restrict__ w9,
        const float* __restrict__ wb, const float* __restrict__ lng,
        const float* __restrict__ lnb, const float* __restrict__ ow3,
        const int* __restrict__ idx, float* __restrict__ pos) {
  int i = blockIdx.x;
  int t = threadIdx.x;
  int iy = idx[2 * i], ix = idx[2 * i + 1];
  int c0 = t * 2;
  int cg0 = c0 & 127, cg1 = cg0 + 1;
  int g = t >> 6;        // wave == group
  int lane = t & 63;
  // depthwise 3x3 at the point (SAME zero-pad)
  float a0 = wb[cg0], a1 = wb[cg1];
#pragma unroll
  for (int dy = 0; dy < 3; ++dy) {
    int hh = iy + dy - 1;
    if (hh < 0 || hh >= HDIM) continue;
#pragma unroll
    for (int dx = 0; dx < 3; ++dx) {
      int ww = ix + dx - 1;
      if (ww < 0 || ww >= WDIM) continue;
      u32 pr2 = *(const u32*)&t1[(hh * WDIM + ww) * C + c0];
      float wt0 = w9[cg0 * 9 + dy * 3 + dx];
      float wt1 = w9[cg1 * 9 + dy * 3 + dx];
      a0 += wt0 * b2f((u16)pr2);
      a1 += wt1 * b2f((u16)(pr2 >> 16));
    }
  }
  // LN over the 128-ch group (wave-local shuffle reduce)
  float s = a0 + a1, s2 = a0 * a0 + a1 * a1;
#pragma unroll
  for (int o = 32; o > 0; o >>= 1) {
    s += __shfl_xor(s, o, 64);
    s2 += __shfl_xor(s2, o, 64);
  }
  float mean = s * (1.0f / 128.0f);
  float var = s2 * (1.0f / 128.0f) - mean * mean;
  float rstd = rsqrtf(var + 1e-5f);
  float xn0 = (a0 - mean) * rstd * lng[cg0] + lnb[cg0];
  float xn1 = (a1 - mean) * rstd * lng[cg1] + lnb[cg1];
  float x0 = 0.5f * xn0 * (1.0f + erff(xn0 * 0.70710678f));
  float x1 = 0.5f * xn1 * (1.0f + erff(xn1 * 0.70710678f));
  // offset matvec: ov[l] = sum_c ow3[l][c] * t2[g][c], 18 wave-reductions
  float ovreg = 0.0f;
#pragma unroll
  for (int l = 0; l < 18; ++l) {
    float a = ow3[l * CG + cg0] * x0 + ow3[l * CG + cg1] * x1;
#pragma unroll
    for (int o = 32; o > 0; o >>= 1) a += __shfl_xor(a, o, 64);
    if (lane == l) ovreg = a;
  }
  // lanes 0..8 -> tanh + reference grid -> pos
  int ls = (lane < 9) ? lane : 0;
  float vy = __shfl(ovreg, 2 * ls, 64);
  float vx = __shfl(ovreg, 2 * ls + 1, 64);
  if (lane < 9) {
    int dy = lane / 3, dx = lane % 3;
    int ryi = min(max(iy + dy - 1, 0), HDIM - 1);
    int rxi = min(max(ix + dx - 1, 0), WDIM - 1);
    float ry = (ryi + 0.5f) * (2.0f / HDIM) - 1.0f;
    float rx = (rxi + 0.5f) * (2.0f / WDIM) - 1.0f;
    f32x2 pv;
    pv.x = tanhf(vy) * (2.0f / HDIM) + ry;
    pv.y = tanhf(vx) * (2.0f / WDIM) + rx;
    *(f32x2*)&pos[((i * G + g) * K + lane) * 2] = pv;
  }
}

// ---------- fused: full-C bilinear sample (-> xr) + attention ----------
// 4 phases / 3 barriers: softmax folded into z-phase (redundant per-wave recompute),
// z-phase reads xsl at consecutive 16B/lane (full bank coverage) + coalesced 1KB row stores.
__global__ void __launch_bounds__(256)
k_attn5(const u16* __restrict__ qk2b, const u16* __restrict__ xtb,
        const float* __restrict__ pos, float* __restrict__ attn_out,
        u16* __restrict__ z2b, float* __restrict__ xr, int n) {
  constexpr int LD = 520;  // row stride (u16) -> 1040 B
  int i = blockIdx.x;
  int t = threadIdx.x;
  __shared__ alignas(16) u16 qkl[8 * LD];
  __shared__ alignas(16) u16 xsl[16 * LD];
  __shared__ int ro[36][4];
  __shared__ float wbl[36][4];
  __shared__ float lg[NH][K];
  // vectorized staging of the 8 KB qk row: 2 x dwordx4 per thread
  {
    const bf16x8* qs = (const bf16x8*)(qk2b + (size_t)i * (NH * C));
#pragma unroll
    for (int cix = t; cix < 512; cix += 256) {
      bf16x8 val = qs[cix];
      int r = cix >> 6;
      int co = (cix & 63) * 8;
      *(bf16x8*)&qkl[r * LD + co] = val;
    }
  }
  // 36 threads precompute bilinear taps once per block
  if (t < 36) {
    float py = pos[(size_t)i * 72 + 2 * t];
    float px = pos[(size_t)i * 72 + 2 * t + 1];
    float gx = (px + 1.0f) * 0.5f * (WDIM - 1);
    float gy = (py + 1.0f) * 0.5f * (HDIM - 1);
    float x0f = floorf(gx), y0f = floorf(gy);
    float wx1 = gx - x0f, wx0 = 1.0f - wx1;
    float wy1 = gy - y0f, wy0 = 1.0f - wy1;
    int x0 = (int)x0f, y0 = (int)y0f;
    int x1 = x0 + 1, y1 = y0 + 1;
    bool vx0 = (x0 >= 0) && (x0 < WDIM);
    bool vx1 = (x1 >= 0) && (x1 < WDIM);
    bool vy0 = (y0 >= 0) && (y0 < HDIM);
    bool vy1 = (y1 >= 0) && (y1 < HDIM);
    wbl[t][0] = (vy0 && vx0) ? wy0 * wx0 : 0.0f;
    wbl[t][1] = (vy0 && vx1) ? wy0 * wx1 : 0.0f;
    wbl[t][2] = (vy1 && vx0) ? wy1 * wx0 : 0.0f;
    wbl[t][3] = (vy1 && vx1) ? wy1 * wx1 : 0.0f;
    int x0c = min(max(x0, 0), WDIM - 1), x1c = min(max(x1, 0), WDIM - 1);
    int y0c = min(max(y0, 0), HDIM - 1), y1c = min(max(y1, 0), HDIM - 1);
    ro[t][0] = (y0c * WDIM + x0c) * C;
    ro[t][1] = (y0c * WDIM + x1c) * C;
    ro[t][2] = (y1c * WDIM + x0c) * C;
    ro[t][3] = (y1c * WDIM + x1c) * C;
  }
  __syncthreads();
  int wave = t >> 6;
  float* xrb = xr + (size_t)i * (G * K) * C;
  // full-C gather: 4 channels/thread, 2 positions in parallel.
  {
    int half = t >> 7;       // 0/1: which position of the pair
    int th = t & 127;
    int c4 = th * 4;         // 4 channels
#pragma unroll 3
    for (int j = 0; j < 18; ++j) {
      int it = 2 * j + half;
      float w00 = wbl[it][0], w01 = wbl[it][1], w10 = wbl[it][2], w11 = wbl[it][3];
      u32x2 q00 = *(const u32x2*)&xtb[ro[it][0] + c4];
      u32x2 q01 = *(const u32x2*)&xtb[ro[it][1] + c4];
      u32x2 q10 = *(const u32x2*)&xtb[ro[it][2] + c4];
      u32x2 q11 = *(const u32x2*)&xtb[ro[it][3] + c4];
      float v0 = w00 * b2f((u16)q00.x) + w01 * b2f((u16)q01.x) +
                 w10 * b2f((u16)q10.x) + w11 * b2f((u16)q11.x);
      float v1 = w00 * b2f((u16)(q00.x >> 16)) + w01 * b2f((u16)(q01.x >> 16)) +
                 w10 * b2f((u16)(q10.x >> 16)) + w11 * b2f((u16)(q11.x >> 16));
      float v2 = w00 * b2f((u16)q00.y) + w01 * b2f((u16)q01.y) +
                 w10 * b2f((u16)q10.y) + w11 * b2f((u16)q11.y);
      float v3 = w00 * b2f((u16)(q00.y >> 16)) + w01 * b2f((u16)(q01.y >> 16)) +
                 w10 * b2f((u16)(q10.y >> 16)) + w11 * b2f((u16)(q11.y >> 16));
      f32x4 ov = {v0, v1, v2, v3};
      __builtin_nontemporal_store(ov, (f32x4*)&xrb[(size_t)it * C + c4]);
      int gi = (it * 57) >> 9;       // it / 9
      if ((th >> 5) == gi) {         // this thread's channels are in group gi's slice
        int kk = it - gi * 9;
        u32x2 pk;
        pk.x = ((u32)f2b(v1) << 16) | f2b(v0);
        pk.y = ((u32)f2b(v3) << 16) | f2b(v2);
        *(u32x2*)&xsl[kk * LD + c4] = pk;
      }
    }
  }
  __syncthreads();
  // logits: one wave, one 16x16 MFMA tile over K=512; A rows 8-15 duplicate rows 0-7 (discarded)
  if (wave == 0) {
    int lane = t & 63;
    int row = lane & 15, quad = lane >> 4;
    f32x4 acc = {};
    __builtin_amdgcn_s_setprio(1);
#pragma unroll 4
    for (int k0 = 0; k0 < C; k0 += 32) {
      bf16x8 a = *(const bf16x8*)&qkl[(row & 7) * LD + k0 + quad * 8];
      bf16x8 b = *(const bf16x8*)&xsl[row * LD + k0 + quad * 8];
      acc = __builtin_amdgcn_mfma_f32_16x16x32_bf16(a, b, acc, 0, 0, 0);
    }
    __builtin_amdgcn_s_setprio(0);
    if (row < K && quad < 2) {
#pragma unroll
      for (int r = 0; r < 4; ++r) lg[quad * 4 + r][row] = acc[r] * SCALE;
    }
  }
  __syncthreads();
  // z-phase + inline softmax: wave w owns heads {2w, 2w+1}; lane l covers chunk l (8 ch).
  {
    int lane = t & 63;
    u16* zrow = z2b + (size_t)i * (NH * C);
#pragma unroll
    for (int hh = 0; hh < 2; ++hh) {
      int h = wave * 2 + hh;
      float mx = -1e30f;
#pragma unroll
      for (int kk = 0; kk < K; ++kk) mx = fmaxf(mx, lg[h][kk]);
      float e[K];
      float sm = 0.0f;
#pragma unroll
      for (int kk = 0; kk < K; ++kk) { e[kk] = expf(lg[h][kk] - mx); sm += e[kk]; }
      float inv = 1.0f / sm;
      if (lane < K) attn_out[((size_t)h * n + i) * K + lane] = e[lane] * inv;
      float accz[8] = {};
#pragma unroll
      for (int kk = 0; kk < K; ++kk) {
        bf16x8 v = *(const bf16x8*)&xsl[kk * LD + lane * 8];
        float p = e[kk] * inv;
#pragma unroll
        for (int el = 0; el < 8; ++el) accz[el] += p * b2f((u16)v[el]);
      }
      u16 ob[8];
#pragma unroll
      for (int el = 0; el < 8; ++el) ob[el] = f2b(accz[el]);
      *(bf16x8*)&zrow[h * C + lane * 8] = *(const bf16x8*)ob;
    }
  }
}

}  // namespace

extern "C" void kernel_launch(void* const* d_in, const int* in_sizes, int n_in,
                              void* d_out, int out_size, void* d_ws, size_t ws_size,
                              hipStream_t stream) {
  (void)n_in; (void)out_size; (void)ws_size;
  const float* x = (const float*)d_in[0];
  const int* idx = (const int*)d_in[1];
  const int* labels = (const int*)d_in[2];
  const float* wq = (const float*)d_in[3];
  const float* bq = (const float*)d_in[4];
  const float* wk = (const float*)d_in[5];
  // bk (d_in[6]) cancels exactly in softmax — unused.
  const float* wv = (const float*)d_in[7];
  const float* bv = (const float*)d_in[8];
  const float* wo = (const float*)d_in[9];
  const float* bo = (const float*)d_in[10];
  const float* ow1 = (const float*)d_in[11];
  const float* ob1 = (const float*)d_in[12];
  const float* g1 = (const float*)d_in[13];
  const float* b1 = (const float*)d_in[14];
  const float* ow2 = (const float*)d_in[15];
  const float* ob2 = (const float*)d_in[16];
  const float* g2 = (const float*)d_in[17];
  const float* b2 = (const float*)d_in[18];
  const float* ow3 = (const float*)d_in[19];
  int n = in_sizes[1] / 2;  // 2048

  unsigned char* wp = (unsigned char*)d_ws;
  auto alloc = [&](size_t bytes) {
    unsigned char* p = wp;
    wp += (bytes + 255) & ~(size_t)255;
    return p;
  };
  u16* xtb = (u16*)alloc((size_t)HW * C * 2);
  u16* wqb = (u16*)alloc((size_t)C * C * 2);
  u16* wvb = (u16*)alloc((size_t)C * C * 2);
  u16* wob = (u16*)alloc((size_t)C * C * 2);
  u16* wkT = (u16*)alloc((size_t)C * C * 2);
  u16* q_tb = (u16*)alloc((size_t)HW * C * 2);
  u16* t1b = (u16*)alloc((size_t)HW * C * 2);
  u16* qk2b = (u16*)alloc((size_t)n * NH * C * 2);
  float* pos = (float*)alloc((size_t)n * G * K * 2 * 4);
  u16* z2b = (u16*)alloc((size_t)n * NH * C * 2);
  u16* outb = (u16*)alloc((size_t)n * C * 2);

  // output layout: y (n,C) | attn (NH,n,K) | xr_sel (n,G*K,C) | sig (n)
  float* out_f = (float*)d_out;
  float* y_out = out_f;
  float* attn_out = y_out + (size_t)n * C;
  float* xr_out = attn_out + (size_t)NH * n * K;
  float* sig_out = xr_out + (size_t)n * G * K * C;

  // prep: weight converts + wkT + x transpose (merged)
  k_prep<<<dim3(3328), 256, 0, stream>>>(wq, wv, wo, wk, x, wqb, wvb, wob, wkT, xtb);

  // GEMM1: q_tb[p][c] = sum_k xtb[p][k] * wqb[c][k] + bq[c]  (bf16 out)
  k_gemm_mfma<true, 512><<<dim3(HW / 64, C / 64, 1), 256, 0, stream>>>(
      xtb, C, 0, nullptr, wqb, C, 0, bq, 0, q_tb, C, 0, nullptr, nullptr);

  // dwln pass-1 (full map)  ||  GEMM2 (per-head q.K projection) — one launch
  k_mix<<<dim3(HW + 2048), 256, 0, stream>>>(q_tb, ow1, ob1, g1, b1, t1b, wkT, idx, qk2b);

  // fused pass-2 + offsets at selected points only
  k_dwoff<<<dim3(n), 256, 0, stream>>>(t1b, ow2, ob2, g2, b2, ow3, idx, pos);

  // fused sample + attention
  k_attn5<<<dim3(n), 256, 0, stream>>>(qk2b, xtb, pos, attn_out, z2b, xr_out, n);

  // GEMM3 (per head): outb[i][h*64+d] = sum_c' z2b[i][h*512+c'] * wvb[h*64+d][c'] + bv
  k_gemm_mfma<true, 512><<<dim3(n / 64, 1, NH), 256, 0, stream>>>(
      z2b, NH * C, C, nullptr, wvb, C, 64 * C, bv, 64, outb, C, 64, nullptr, nullptr);

  // GEMM4: y[i][co] = sum_c outb[i][c] * wob[co][c] + bo[co]  (fp32 out) + fused sigmoid
  k_gemm_mfma<false, 512><<<dim3(n / 64, C / 64, 1), 256, 0, stream>>>(
      outb, C, 0, nullptr, wob, C, 0, bo, 0, y_out, C, 0, labels, sig_out);
}

// Round 9
// 299.598 us; speedup vs baseline: 1.0862x; 1.0199x over previous
//
#include <hip/hip_runtime.h>
#include <math.h>

namespace {

typedef unsigned short u16;
typedef unsigned int u32;
typedef __attribute__((ext_vector_type(8))) short bf16x8;
typedef __attribute__((ext_vector_type(4))) float f32x4;
typedef __attribute__((ext_vector_type(2))) float f32x2;
typedef __attribute__((ext_vector_type(2))) unsigned int u32x2;

constexpr int HDIM = 64;
constexpr int WDIM = 64;
constexpr int HW = HDIM * WDIM;   // 4096
constexpr int C = 512;
constexpr int G = 4;
constexpr int CG = 128;
constexpr int K = 9;
constexpr int NH = 8;
constexpr float SCALE = 0.125f;   // DH^-0.5

__device__ __forceinline__ u16 f2b(float f) {
  union { float f; u32 u; } v; v.f = f;
  u32 u = v.u;
  return (u16)((u + 0x7FFFu + ((u >> 16) & 1u)) >> 16);
}
__device__ __forceinline__ float b2f(u16 b) {
  union { u32 u; float f; } v; v.u = ((u32)b) << 16;
  return v.f;
}

// ---------- merged one-time prep: wq/wv/wo->bf16, wkT, x transpose ----------
// blocks [0,1024): convert3; [1024,1280): wkT; [1280,3328): transpose
__global__ void __launch_bounds__(256)
k_prep(const float* __restrict__ wq, const float* __restrict__ wv,
       const float* __restrict__ wo, const float* __restrict__ wk,
       const float* __restrict__ x,
       u16* __restrict__ wqb, u16* __restrict__ wvb, u16* __restrict__ wob,
       u16* __restrict__ wkT, u16* __restrict__ xtb) {
  int b = blockIdx.x;
  int t = threadIdx.x;
  if (b < 1024) {
    int j = b * 256 + t;
    wqb[j] = f2b(wq[j]);
    wvb[j] = f2b(wv[j]);
    wob[j] = f2b(wo[j]);
    return;
  }
  __shared__ float tile[32][33];
  int tx = t & 31, ty = t >> 5;
  if (b < 1280) {
    int bb = b - 1024;                       // grid was (16,16)
    int r0 = (bb & 15) * 32, c0 = (bb >> 4) * 32;
    for (int r = ty; r < 32; r += 8) tile[r][tx] = wk[(r0 + r) * C + c0 + tx];
    __syncthreads();
    for (int r = ty; r < 32; r += 8) wkT[(c0 + r) * C + r0 + tx] = f2b(tile[tx][r]);
  } else {
    int bb = b - 1280;                       // grid was (128,16)
    int p0 = (bb & 127) * 32, c0 = (bb >> 7) * 32;
    for (int r = ty; r < 32; r += 8) tile[r][tx] = x[(c0 + r) * HW + p0 + tx];
    __syncthreads();
    for (int r = ty; r < 32; r += 8) xtb[(p0 + r) * C + c0 + tx] = f2b(tile[tx][r]);
  }
}

// ---------- unified bf16 MFMA GEMM: D[m][n] = sum_k A[m][k] * BT[n][k] (+bias[n]) ----------
template <bool OUT_BF16>
__global__ void __launch_bounds__(256)
k_gemm_mfma(const u16* __restrict__ A, int lda, int aOffZ,
            const int* __restrict__ aIdx,
            const u16* __restrict__ BT, int ldb, int bOffZ,
            const float* __restrict__ bias, int biasOffZ,
            void* __restrict__ Dp, int ldd, int dOffZ, int Kd,
            const int* __restrict__ labels, float* __restrict__ sigp) {
  int z = blockIdx.z;
  const u16* Ab = A + (size_t)z * aOffZ;
  const u16* Bb = BT + (size_t)z * bOffZ;
  int t = threadIdx.x;
  int wave = t >> 6, lane = t & 63;
  int wm = (wave >> 1) * 32, wn = (wave & 1) * 32;
  int bm = blockIdx.x * 64 + wm;
  int bn = blockIdx.y * 64 + wn;
  int row = lane & 15, quad = lane >> 4;
  size_t ar[2];
#pragma unroll
  for (int mt = 0; mt < 2; ++mt) {
    int r = bm + mt * 16 + row;
    ar[mt] = aIdx ? (size_t)(aIdx[2 * r] * WDIM + aIdx[2 * r + 1]) : (size_t)r;
  }
  f32x4 acc[2][2] = {};
  for (int k0 = 0; k0 < Kd; k0 += 32) {
    bf16x8 a[2], b[2];
#pragma unroll
    for (int mt = 0; mt < 2; ++mt)
      a[mt] = *(const bf16x8*)&Ab[ar[mt] * lda + k0 + quad * 8];
#pragma unroll
    for (int nt = 0; nt < 2; ++nt)
      b[nt] = *(const bf16x8*)&Bb[(size_t)(bn + nt * 16 + row) * ldb + k0 + quad * 8];
#pragma unroll
    for (int mt = 0; mt < 2; ++mt)
#pragma unroll
      for (int nt = 0; nt < 2; ++nt)
        acc[mt][nt] = __builtin_amdgcn_mfma_f32_16x16x32_bf16(a[mt], b[nt], acc[mt][nt], 0, 0, 0);
  }
#pragma unroll
  for (int nt = 0; nt < 2; ++nt) {
    int cc = bn + nt * 16 + row;
    float bb = bias ? bias[(size_t)z * biasOffZ + cc] : 0.0f;
#pragma unroll
    for (int mt = 0; mt < 2; ++mt)
#pragma unroll
      for (int r = 0; r < 4; ++r) {
        int rr = bm + mt * 16 + quad * 4 + r;
        float v = acc[mt][nt][r] + bb;
        if (OUT_BF16) {
          ((u16*)Dp)[(size_t)z * dOffZ + (size_t)rr * ldd + cc] = f2b(v);
        } else {
          ((float*)Dp)[(size_t)z * dOffZ + (size_t)rr * ldd + cc] = v;
          if (labels && labels[rr] == cc) sigp[rr] = 1.0f / (1.0f + expf(-v));
        }
      }
  }
}

// ---------- merged: dwconv+LN+GELU full map (blocks [0,HW)) || GEMM2 (blocks [HW,HW+2048)) ----------
// the two halves are data-independent (both read q_tb) and fill the machine concurrently.
__global__ void __launch_bounds__(256)
k_mix(const u16* __restrict__ q_tb, const float* __restrict__ w9,
      const float* __restrict__ wb, const float* __restrict__ lng,
      const float* __restrict__ lnb, u16* __restrict__ t1b,
      const u16* __restrict__ wkT, const int* __restrict__ idx,
      u16* __restrict__ qk2b) {
  int b = blockIdx.x;
  int t = threadIdx.x;
  if (b < HW) {
    // ---- dwln2 path: one spatial position, 2 channels/thread, wave == LN group ----
    int p = b;
    int h = p >> 6, w = p & 63;
    int c0 = t * 2;
    int cg0 = c0 & 127, cg1 = cg0 + 1;
    float a0 = wb[cg0], a1 = wb[cg1];
#pragma unroll
    for (int dy = 0; dy < 3; ++dy) {
      int hh = h + dy - 1;
      if (hh < 0 || hh >= HDIM) continue;
#pragma unroll
      for (int dx = 0; dx < 3; ++dx) {
        int ww = w + dx - 1;
        if (ww < 0 || ww >= WDIM) continue;
        u32 pr2 = *(const u32*)&q_tb[(hh * WDIM + ww) * C + c0];
        float wt0 = w9[cg0 * 9 + dy * 3 + dx];
        float wt1 = w9[cg1 * 9 + dy * 3 + dx];
        a0 += wt0 * b2f((u16)pr2);
        a1 += wt1 * b2f((u16)(pr2 >> 16));
      }
    }
    float s = a0 + a1, s2 = a0 * a0 + a1 * a1;
#pragma unroll
    for (int o = 32; o > 0; o >>= 1) {
      s += __shfl_xor(s, o, 64);
      s2 += __shfl_xor(s2, o, 64);
    }
    float mean = s * (1.0f / 128.0f);
    float var = s2 * (1.0f / 128.0f) - mean * mean;
    float rstd = rsqrtf(var + 1e-5f);
    float xn0 = (a0 - mean) * rstd * lng[cg0] + lnb[cg0];
    float xn1 = (a1 - mean) * rstd * lng[cg1] + lnb[cg1];
    u16 o0 = f2b(0.5f * xn0 * (1.0f + erff(xn0 * 0.70710678f)));
    u16 o1 = f2b(0.5f * xn1 * (1.0f + erff(xn1 * 0.70710678f)));
    *(u32*)&t1b[(size_t)p * C + c0] = ((u32)o1 << 16) | o0;
  } else {
    // ---- GEMM2 path: qk2b[i][z*512+c'] = sum_d q_tb[p_i][z*64+d] * wkT[c'][z*64+d] ----
    int bb = b - HW;                  // 0..2047
    int m = bb & 31, nn = (bb >> 5) & 7, z = bb >> 8;
    const u16* Ab = q_tb + z * 64;
    const u16* Bb = wkT + z * 64;
    int wave = t >> 6, lane = t & 63;
    int wm = (wave >> 1) * 32, wn = (wave & 1) * 32;
    int bm = m * 64 + wm;
    int bn = nn * 64 + wn;
    int row = lane & 15, quad = lane >> 4;
    size_t ar[2];
#pragma unroll
    for (int mt = 0; mt < 2; ++mt) {
      int r = bm + mt * 16 + row;
      ar[mt] = (size_t)(idx[2 * r] * WDIM + idx[2 * r + 1]);
    }
    f32x4 acc[2][2] = {};
#pragma unroll
    for (int k0 = 0; k0 < 64; k0 += 32) {
      bf16x8 a[2], bfr[2];
#pragma unroll
      for (int mt = 0; mt < 2; ++mt)
        a[mt] = *(const bf16x8*)&Ab[ar[mt] * C + k0 + quad * 8];
#pragma unroll
      for (int nt = 0; nt < 2; ++nt)
        bfr[nt] = *(const bf16x8*)&Bb[(size_t)(bn + nt * 16 + row) * C + k0 + quad * 8];
#pragma unroll
      for (int mt = 0; mt < 2; ++mt)
#pragma unroll
        for (int nt = 0; nt < 2; ++nt)
          acc[mt][nt] = __builtin_amdgcn_mfma_f32_16x16x32_bf16(a[mt], bfr[nt], acc[mt][nt], 0, 0, 0);
    }
#pragma unroll
    for (int nt = 0; nt < 2; ++nt) {
      int cc = bn + nt * 16 + row;
#pragma unroll
      for (int mt = 0; mt < 2; ++mt)
#pragma unroll
        for (int r = 0; r < 4; ++r) {
          int rr = bm + mt * 16 + quad * 4 + r;
          qk2b[(size_t)rr * (NH * C) + z * C + cc] = f2b(acc[mt][nt][r]);
        }
    }
  }
}

// ---------- fully fused per-point kernel: offsets (dwconv+LN+GELU+matvec+tanh) ----------
// ---------- + full-C bilinear sample (-> xr) + attention (MFMA/softmax/z) ----------
// dwoff absorbed into the attn preamble: wave == group computes its own 9 taps in
// registers; lanes 0-8 do the bilinear setup directly (no 36-thread phase, no pos
// round-trip). Same 3-barrier structure as the round-6 kernel.
__global__ void __launch_bounds__(256)
k_attn6(const u16* __restrict__ t1, const float* __restrict__ w9,
        const float* __restrict__ wb, const float* __restrict__ lng,
        const float* __restrict__ lnb, const float* __restrict__ ow3,
        const int* __restrict__ idx,
        const u16* __restrict__ qk2b, const u16* __restrict__ xtb,
        float* __restrict__ attn_out, u16* __restrict__ z2b,
        float* __restrict__ xr, int n) {
  constexpr int LD = 520;  // row stride (u16) -> 1040 B
  int i = blockIdx.x;
  int t = threadIdx.x;
  __shared__ alignas(16) u16 qkl[8 * LD];
  __shared__ alignas(16) u16 xsl[16 * LD];
  __shared__ int ro[36][4];
  __shared__ float wbl[36][4];
  __shared__ float lg[NH][K];
  int wave = t >> 6, lane = t & 63;
  int iy = idx[2 * i], ix = idx[2 * i + 1];
  // ---- phase 0a: stage the 8 KB qk row (issued first; latency overlaps dwoff body) ----
  {
    const bf16x8* qs = (const bf16x8*)(qk2b + (size_t)i * (NH * C));
#pragma unroll
    for (int cix = t; cix < 512; cix += 256) {
      bf16x8 val = qs[cix];
      int r = cix >> 6;
      int co = (cix & 63) * 8;
      *(bf16x8*)&qkl[r * LD + co] = val;
    }
  }
  // ---- phase 0b: dwoff body (registers + shuffles only); wave == group ----
  {
    int c0 = t * 2;
    int cg0 = c0 & 127, cg1 = cg0 + 1;
    int g = wave;
    float a0 = wb[cg0], a1 = wb[cg1];
#pragma unroll
    for (int dy = 0; dy < 3; ++dy) {
      int hh = iy + dy - 1;
      if (hh < 0 || hh >= HDIM) continue;
#pragma unroll
      for (int dx = 0; dx < 3; ++dx) {
        int ww = ix + dx - 1;
        if (ww < 0 || ww >= WDIM) continue;
        u32 pr2 = *(const u32*)&t1[(hh * WDIM + ww) * C + c0];
        float wt0 = w9[cg0 * 9 + dy * 3 + dx];
        float wt1 = w9[cg1 * 9 + dy * 3 + dx];
        a0 += wt0 * b2f((u16)pr2);
        a1 += wt1 * b2f((u16)(pr2 >> 16));
      }
    }
    float s = a0 + a1, s2 = a0 * a0 + a1 * a1;
#pragma unroll
    for (int o = 32; o > 0; o >>= 1) {
      s += __shfl_xor(s, o, 64);
      s2 += __shfl_xor(s2, o, 64);
    }
    float mean = s * (1.0f / 128.0f);
    float var = s2 * (1.0f / 128.0f) - mean * mean;
    float rstd = rsqrtf(var + 1e-5f);
    float xn0 = (a0 - mean) * rstd * lng[cg0] + lnb[cg0];
    float xn1 = (a1 - mean) * rstd * lng[cg1] + lnb[cg1];
    float x0 = 0.5f * xn0 * (1.0f + erff(xn0 * 0.70710678f));
    float x1 = 0.5f * xn1 * (1.0f + erff(xn1 * 0.70710678f));
    float ovreg = 0.0f;
#pragma unroll
    for (int l = 0; l < 18; ++l) {
      float a = ow3[l * CG + cg0] * x0 + ow3[l * CG + cg1] * x1;
#pragma unroll
      for (int o = 32; o > 0; o >>= 1) a += __shfl_xor(a, o, 64);
      if (lane == l) ovreg = a;
    }
    int ls = (lane < 9) ? lane : 0;
    float vy = __shfl(ovreg, 2 * ls, 64);
    float vx = __shfl(ovreg, 2 * ls + 1, 64);
    if (lane < 9) {
      int dy = lane / 3, dx = lane % 3;
      int ryi = min(max(iy + dy - 1, 0), HDIM - 1);
      int rxi = min(max(ix + dx - 1, 0), WDIM - 1);
      float ry = (ryi + 0.5f) * (2.0f / HDIM) - 1.0f;
      float rx = (rxi + 0.5f) * (2.0f / WDIM) - 1.0f;
      float py = tanhf(vy) * (2.0f / HDIM) + ry;
      float px = tanhf(vx) * (2.0f / WDIM) + rx;
      // bilinear setup for this wave's tap (g, lane) -> it = g*9+lane
      int it = g * 9 + lane;
      float gx = (px + 1.0f) * 0.5f * (WDIM - 1);
      float gy = (py + 1.0f) * 0.5f * (HDIM - 1);
      float x0f = floorf(gx), y0f = floorf(gy);
      float wx1 = gx - x0f, wx0 = 1.0f - wx1;
      float wy1 = gy - y0f, wy0 = 1.0f - wy1;
      int bx0 = (int)x0f, by0 = (int)y0f;
      int bx1 = bx0 + 1, by1 = by0 + 1;
      bool vx0 = (bx0 >= 0) && (bx0 < WDIM);
      bool vx1b = (bx1 >= 0) && (bx1 < WDIM);
      bool vy0 = (by0 >= 0) && (by0 < HDIM);
      bool vy1b = (by1 >= 0) && (by1 < HDIM);
      wbl[it][0] = (vy0 && vx0) ? wy0 * wx0 : 0.0f;
      wbl[it][1] = (vy0 && vx1b) ? wy0 * wx1 : 0.0f;
      wbl[it][2] = (vy1b && vx0) ? wy1 * wx0 : 0.0f;
      wbl[it][3] = (vy1b && vx1b) ? wy1 * wx1 : 0.0f;
      int x0c = min(max(bx0, 0), WDIM - 1), x1c = min(max(bx1, 0), WDIM - 1);
      int y0c = min(max(by0, 0), HDIM - 1), y1c = min(max(by1, 0), HDIM - 1);
      ro[it][0] = (y0c * WDIM + x0c) * C;
      ro[it][1] = (y0c * WDIM + x1c) * C;
      ro[it][2] = (y1c * WDIM + x0c) * C;
      ro[it][3] = (y1c * WDIM + x1c) * C;
    }
  }
  __syncthreads();
  float* xrb = xr + (size_t)i * (G * K) * C;
  // ---- phase 1: full-C gather, 4 channels/thread, 2 positions in parallel ----
  {
    int half = t >> 7;       // 0/1: which position of the pair
    int th = t & 127;
    int c4 = th * 4;         // 4 channels
#pragma unroll 3
    for (int j = 0; j < 18; ++j) {
      int it = 2 * j + half;
      float w00 = wbl[it][0], w01 = wbl[it][1], w10 = wbl[it][2], w11 = wbl[it][3];
      u32x2 q00 = *(const u32x2*)&xtb[ro[it][0] + c4];
      u32x2 q01 = *(const u32x2*)&xtb[ro[it][1] + c4];
      u32x2 q10 = *(const u32x2*)&xtb[ro[it][2] + c4];
      u32x2 q11 = *(const u32x2*)&xtb[ro[it][3] + c4];
      float v0 = w00 * b2f((u16)q00.x) + w01 * b2f((u16)q01.x) +
                 w10 * b2f((u16)q10.x) + w11 * b2f((u16)q11.x);
      float v1 = w00 * b2f((u16)(q00.x >> 16)) + w01 * b2f((u16)(q01.x >> 16)) +
                 w10 * b2f((u16)(q10.x >> 16)) + w11 * b2f((u16)(q11.x >> 16));
      float v2 = w00 * b2f((u16)q00.y) + w01 * b2f((u16)q01.y) +
                 w10 * b2f((u16)q10.y) + w11 * b2f((u16)q11.y);
      float v3 = w00 * b2f((u16)(q00.y >> 16)) + w01 * b2f((u16)(q01.y >> 16)) +
                 w10 * b2f((u16)(q10.y >> 16)) + w11 * b2f((u16)(q11.y >> 16));
      f32x4 ov = {v0, v1, v2, v3};
      __builtin_nontemporal_store(ov, (f32x4*)&xrb[(size_t)it * C + c4]);
      int gi = (it * 57) >> 9;       // it / 9
      if ((th >> 5) == gi) {         // this thread's channels are in group gi's slice
        int kk = it - gi * 9;
        u32x2 pk;
        pk.x = ((u32)f2b(v1) << 16) | f2b(v0);
        pk.y = ((u32)f2b(v3) << 16) | f2b(v2);
        *(u32x2*)&xsl[kk * LD + c4] = pk;
      }
    }
  }
  __syncthreads();
  // ---- phase 2: logits, one wave; A rows 8-15 duplicate rows 0-7 (discarded) ----
  if (wave == 0) {
    int row = lane & 15, quad = lane >> 4;
    f32x4 acc = {};
    __builtin_amdgcn_s_setprio(1);
#pragma unroll 4
    for (int k0 = 0; k0 < C; k0 += 32) {
      bf16x8 a = *(const bf16x8*)&qkl[(row & 7) * LD + k0 + quad * 8];
      bf16x8 b = *(const bf16x8*)&xsl[row * LD + k0 + quad * 8];
      acc = __builtin_amdgcn_mfma_f32_16x16x32_bf16(a, b, acc, 0, 0, 0);
    }
    __builtin_amdgcn_s_setprio(0);
    if (row < K && quad < 2) {
#pragma unroll
      for (int r = 0; r < 4; ++r) lg[quad * 4 + r][row] = acc[r] * SCALE;
    }
  }
  __syncthreads();
  // ---- phase 3: z + inline softmax; wave w owns heads {2w, 2w+1} ----
  {
    u16* zrow = z2b + (size_t)i * (NH * C);
#pragma unroll
    for (int hh = 0; hh < 2; ++hh) {
      int h = wave * 2 + hh;
      float mx = -1e30f;
#pragma unroll
      for (int kk = 0; kk < K; ++kk) mx = fmaxf(mx, lg[h][kk]);
      float e[K];
      float sm = 0.0f;
#pragma unroll
      for (int kk = 0; kk < K; ++kk) { e[kk] = expf(lg[h][kk] - mx); sm += e[kk]; }
      float inv = 1.0f / sm;
      if (lane < K) attn_out[((size_t)h * n + i) * K + lane] = e[lane] * inv;
      float accz[8] = {};
#pragma unroll
      for (int kk = 0; kk < K; ++kk) {
        bf16x8 v = *(const bf16x8*)&xsl[kk * LD + lane * 8];
        float p = e[kk] * inv;
#pragma unroll
        for (int el = 0; el < 8; ++el) accz[el] += p * b2f((u16)v[el]);
      }
      u16 ob[8];
#pragma unroll
      for (int el = 0; el < 8; ++el) ob[el] = f2b(accz[el]);
      *(bf16x8*)&zrow[h * C + lane * 8] = *(const bf16x8*)ob;
    }
  }
}

}  // namespace

extern "C" void kernel_launch(void* const* d_in, const int* in_sizes, int n_in,
                              void* d_out, int out_size, void* d_ws, size_t ws_size,
                              hipStream_t stream) {
  (void)n_in; (void)out_size; (void)ws_size;
  const float* x = (const float*)d_in[0];
  const int* idx = (const int*)d_in[1];
  const int* labels = (const int*)d_in[2];
  const float* wq = (const float*)d_in[3];
  const float* bq = (const float*)d_in[4];
  const float* wk = (const float*)d_in[5];
  // bk (d_in[6]) cancels exactly in softmax — unused.
  const float* wv = (const float*)d_in[7];
  const float* bv = (const float*)d_in[8];
  const float* wo = (const float*)d_in[9];
  const float* bo = (const float*)d_in[10];
  const float* ow1 = (const float*)d_in[11];
  const float* ob1 = (const float*)d_in[12];
  const float* g1 = (const float*)d_in[13];
  const float* b1 = (const float*)d_in[14];
  const float* ow2 = (const float*)d_in[15];
  const float* ob2 = (const float*)d_in[16];
  const float* g2 = (const float*)d_in[17];
  const float* b2 = (const float*)d_in[18];
  const float* ow3 = (const float*)d_in[19];
  int n = in_sizes[1] / 2;  // 2048

  unsigned char* wp = (unsigned char*)d_ws;
  auto alloc = [&](size_t bytes) {
    unsigned char* p = wp;
    wp += (bytes + 255) & ~(size_t)255;
    return p;
  };
  u16* xtb = (u16*)alloc((size_t)HW * C * 2);
  u16* wqb = (u16*)alloc((size_t)C * C * 2);
  u16* wvb = (u16*)alloc((size_t)C * C * 2);
  u16* wob = (u16*)alloc((size_t)C * C * 2);
  u16* wkT = (u16*)alloc((size_t)C * C * 2);
  u16* q_tb = (u16*)alloc((size_t)HW * C * 2);
  u16* t1b = (u16*)alloc((size_t)HW * C * 2);
  u16* qk2b = (u16*)alloc((size_t)n * NH * C * 2);
  u16* z2b = (u16*)alloc((size_t)n * NH * C * 2);
  u16* outb = (u16*)alloc((size_t)n * C * 2);

  // output layout: y (n,C) | attn (NH,n,K) | xr_sel (n,G*K,C) | sig (n)
  float* out_f = (float*)d_out;
  float* y_out = out_f;
  float* attn_out = y_out + (size_t)n * C;
  float* xr_out = attn_out + (size_t)NH * n * K;
  float* sig_out = xr_out + (size_t)n * G * K * C;

  // prep: weight converts + wkT + x transpose (merged)
  k_prep<<<dim3(3328), 256, 0, stream>>>(wq, wv, wo, wk, x, wqb, wvb, wob, wkT, xtb);

  // GEMM1: q_tb[p][c] = sum_k xtb[p][k] * wqb[c][k] + bq[c]  (bf16 out)
  k_gemm_mfma<true><<<dim3(HW / 64, C / 64, 1), 256, 0, stream>>>(
      xtb, C, 0, nullptr, wqb, C, 0, bq, 0, q_tb, C, 0, C, nullptr, nullptr);

  // dwln pass-1 (full map)  ||  GEMM2 (per-head q.K projection) — one launch
  k_mix<<<dim3(HW + 2048), 256, 0, stream>>>(q_tb, ow1, ob1, g1, b1, t1b, wkT, idx, qk2b);

  // fully fused: offsets (dwconv pass-2 at points) + sample + attention
  k_attn6<<<dim3(n), 256, 0, stream>>>(t1b, ow2, ob2, g2, b2, ow3, idx,
                                       qk2b, xtb, attn_out, z2b, xr_out, n);

  // GEMM3 (per head): outb[i][h*64+d] = sum_c' z2b[i][h*512+c'] * wvb[h*64+d][c'] + bv
  k_gemm_mfma<true><<<dim3(n / 64, 1, NH), 256, 0, stream>>>(
      z2b, NH * C, C, nullptr, wvb, C, 64 * C, bv, 64, outb, C, 64, C, nullptr, nullptr);

  // GEMM4: y[i][co] = sum_c outb[i][c] * wob[co][c] + bo[co]  (fp32 out) + fused sigmoid
  k_gemm_mfma<false><<<dim3(n / 64, C / 64, 1), 256, 0, stream>>>(
      outb, C, 0, nullptr, wob, C, 0, bo, 0, y_out, C, 0, C, labels, sig_out);
}